// Round 7
// baseline (119.282 us; speedup 1.0000x reference)
//
#include <hip/hip_runtime.h>
#include <stdint.h>

// Problem constants
#define B_      16
#define N_      2048
#define M_      8192
#define ROWS    (B_ * N_)        // 32768
#define D_      8

// ---- MFMA argmin tiling ----
#define QUARTERS 8               // splits of the anchor set (r7: 4->8 for occupancy)
#define APQ     (M_ / QUARTERS)  // 1024 anchors per split
#define CHUNK   256              // anchors per LDS chunk
#define NCHUNK  (APQ / CHUNK)    // 4
#define TPC     (CHUNK / 16)     // 16 MFMA tiles per chunk
#define WROWS   64               // rows per wave (4 subtiles of 16)
#define BROWS_A 256              // rows per block (4 waves)
#define GRIDX   (ROWS / BROWS_A) // 128 -> grid 128x8 = 1024 blocks (4/CU)

// Packed-anchor plane layout (same layout in ws prep region and LDS buffer)
#define OFF_NH  0                // [256][8] bf16 hi   (4 KB)
#define OFF_NM  4096             // [256][8] bf16 mid  (4 KB)
#define OFF_NL  8192             // [256][8] bf16 lo   (4 KB)
#define OFF_HN  12288            // [256]    f32 0.5*||a||^2 (1 KB)
#define CHUNK_BYTES 13312        // 13 KB, 16B-aligned
#define CHUNK_F4    (CHUNK_BYTES / 16)  // 832 float4
// 36 KB declared (2 bufs = 26 KB used): occupancy governor -> exactly 4
// blocks/CU (160/36) = 16 waves/CU = 4 waves/SIMD -> VGPR budget 128 >= 88
// measured. NOT less LDS: 6 blocks/CU would set an ~85-VGPR target < 88 and
// re-trigger the r0/r2 AGPR-shunt pathology. NOT more: r6's 2 blocks/CU was
// the latency-bound bottleneck (68us @ 640cy/tile vs ~150cy issue work,
// Occupancy 20%, chains ds_read~120cy + 2 serial MFMA unhidden).
#define SMEM_BYTES 36864

// History (hard-won; keep):
//  r0-r4: scalar VALU path pinned at 59-76us across 4 structures (practical
//    v_fma_f32 ceiling ~103 TF -> scalar floor ~47us; r4: 64us @ 90% busy).
//  r5: MFMA split-bf16 argmin CORRECT but 116us: full unroll + in-kernel
//    conversion -> 14MB scratch spills (WRITE_SIZE), occupancy 11%.
//  r6: prep kernel + unroll-2 killed spills (WRITE 1024KB, VGPR 88) -> 68us,
//    but 2 blocks/CU left chains unhidden (latency-bound).
//  r7: QUARTERS 4->8 doubles resident waves; per-tile math byte-identical.
//  MFMA numerics: x,-a split hi/mid/lo bf16 (RNE); two 16x16x32 MFMAs give
//  8 of 9 cross terms (drop ll ~2^-36); C-input carries 0.5||a||^2.

typedef short bf16x8 __attribute__((ext_vector_type(8)));
typedef float f32x4  __attribute__((ext_vector_type(4)));

__device__ __forceinline__ unsigned short f2bf(float f) {   // RNE f32->bf16
    unsigned u = __float_as_uint(f);
    u += 0x7FFFu + ((u >> 16) & 1u);
    return (unsigned short)(u >> 16);
}
__device__ __forceinline__ float bf2f(unsigned short h) {
    return __uint_as_float(((unsigned)h) << 16);
}

// Prep: one thread per anchor; split negated anchor into bf16 hi/mid/lo +
// f32 half-norm. Chain BIT-IDENTICAL to r5/r6 (verified passing).
__global__ __launch_bounds__(256) void prep_kernel(
    const float* __restrict__ anchors, char* __restrict__ pk)
{
    const int a = blockIdx.x * 256 + threadIdx.x;
    const float4* pa = (const float4*)(anchors + (size_t)a * D_);
    const float4 g0 = pa[0], g1 = pa[1];
    float nv[8] = {-g0.x, -g0.y, -g0.z, -g0.w, -g1.x, -g1.y, -g1.z, -g1.w};
    bf16x8 vh, vm, vl;
    #pragma unroll
    for (int k = 0; k < 8; ++k) {
        unsigned short h = f2bf(nv[k]);
        float r1 = nv[k] - bf2f(h);
        unsigned short m = f2bf(r1);
        float r2 = r1 - bf2f(m);
        unsigned short l = f2bf(r2);
        vh[k] = (short)h; vm[k] = (short)m; vl[k] = (short)l;
    }
    char* base = pk + (size_t)(a >> 8) * CHUNK_BYTES;
    const int i = a & 255;
    *(bf16x8*)(base + OFF_NH + i * 16) = vh;
    *(bf16x8*)(base + OFF_NM + i * 16) = vm;
    *(bf16x8*)(base + OFF_NL + i * 16) = vl;
    float nr = nv[0] * nv[0];
    #pragma unroll
    for (int k = 1; k < 8; ++k) nr = fmaf(nv[k], nv[k], nr);
    *(float*)(base + OFF_HN + i * 4) = 0.5f * nr;
}

// Kernel A: per-(row, split) (min score, argmin index) via split-bf16 MFMA.
// Wave owns 64 rows; sweeps its split's 1024 anchors in 4 double-buffered
// 13KB LDS chunks (flat float4 copy from the prep region — no conversion).
// C/D layout (m89/m91, r5-verified): col = lane&15, row = (lane>>4)*4 + reg.
__global__ __launch_bounds__(256) void argmin_mfma_kernel(
    const float* __restrict__ x,        // [ROWS][8]
    const char*  __restrict__ pk,       // packed anchors, 32 chunks
    float* __restrict__ wsv,            // [QUARTERS][ROWS]
    int*   __restrict__ wsi)            // [QUARTERS][ROWS]
{
    __shared__ __align__(16) char smem[SMEM_BYTES];

    const int tid  = threadIdx.x;
    const int wave = tid >> 6;
    const int lane = tid & 63;
    const int n    = lane & 15;          // B col / C col slot
    const int kb   = lane >> 4;          // k-block 0..3

    const int quarter = blockIdx.y;
    const int abase   = quarter * APQ;
    const int wrow0   = blockIdx.x * BROWS_A + wave * WROWS;

    // A fragments: x split hi/mid/lo, virtual K=32 packing
    // A1 = [xh, xm, xh, xm], A2 = [xh, xl, xm, xl]  (identical to r5/r6)
    bf16x8 A1[4], A2[4];
    #pragma unroll
    for (int rt = 0; rt < 4; ++rt) {
        const int row = wrow0 + rt * 16 + n;
        const float4* px = (const float4*)(x + (size_t)row * D_);
        const float4 lo = px[0], hi = px[1];
        const float v[8] = {lo.x, lo.y, lo.z, lo.w, hi.x, hi.y, hi.z, hi.w};
        const bool odd = (kb & 1);
        const bool is2 = (kb == 2);
        #pragma unroll
        for (int k = 0; k < 8; ++k) {
            unsigned short xh = f2bf(v[k]);
            float r1 = v[k] - bf2f(xh);
            unsigned short xm = f2bf(r1);
            float r2 = r1 - bf2f(xm);
            unsigned short xl = f2bf(r2);
            A1[rt][k] = (short)(odd ? xm : xh);
            A2[rt][k] = (short)(odd ? xl : (is2 ? xm : xh));
        }
    }

    // Per-lane LDS read offsets. B1 = [nh,nh,nm,nm]; B2 = [nl,nh,nl,nm].
    const int o1 = ((kb < 2) ? OFF_NH : OFF_NM) + n * 16;
    const int o2 = ((kb == 1) ? OFF_NH : (kb == 3) ? OFF_NM : OFF_NL) + n * 16;
    const int oh = OFF_HN + n * 4;

    float best[4][4];
    int   bidx[4][4];
    #pragma unroll
    for (int rt = 0; rt < 4; ++rt)
        #pragma unroll
        for (int q = 0; q < 4; ++q) { best[rt][q] = 3.4e38f; bidx[rt][q] = 0; }

    int idxv = abase + n;

    const float4* srcq = (const float4*)(pk + (size_t)quarter * NCHUNK * CHUNK_BYTES);
    const bool w0 = (tid < 64);          // wave-0-uniform branch

    // Stage chunk 0 (flat copy: 832 float4 over 256 threads)
    {
        float4* b = (float4*)smem;
        b[tid]       = srcq[tid];
        b[tid + 256] = srcq[tid + 256];
        b[tid + 512] = srcq[tid + 512];
        if (w0) b[tid + 768] = srcq[tid + 768];
    }
    __syncthreads();

    #pragma unroll 1
    for (int c = 0; c < NCHUNK; ++c) {
        const char* bufr = smem + (c & 1) * CHUNK_BYTES;

        float4 s0, s1, s2, s3;               // T14: issue next chunk's loads
        if (c < NCHUNK - 1) {                // early, write to LDS after tiles
            const float4* src = srcq + (size_t)(c + 1) * CHUNK_F4;
            s0 = src[tid];
            s1 = src[tid + 256];
            s2 = src[tid + 512];
            if (w0) s3 = src[tid + 768];
        }

        #pragma unroll 2
        for (int tt = 0; tt < TPC; ++tt) {
            const bf16x8 b1 = *(const bf16x8*)(bufr + o1 + tt * 256);
            const bf16x8 b2 = *(const bf16x8*)(bufr + o2 + tt * 256);
            const float  hn = *(const float*)(bufr + oh + tt * 64);
            const f32x4 cvec = {hn, hn, hn, hn};
            #pragma unroll
            for (int rt = 0; rt < 4; ++rt) {
                f32x4 acc = __builtin_amdgcn_mfma_f32_16x16x32_bf16(A1[rt], b1, cvec, 0, 0, 0);
                acc = __builtin_amdgcn_mfma_f32_16x16x32_bf16(A2[rt], b2, acc, 0, 0, 0);
                #pragma unroll
                for (int q = 0; q < 4; ++q) {
                    const bool lt = acc[q] < best[rt][q];   // strict '<': keeps
                    best[rt][q] = lt ? acc[q] : best[rt][q];// earliest index
                    bidx[rt][q] = lt ? idxv   : bidx[rt][q];
                }
            }
            idxv += 16;
        }

        if (c < NCHUNK - 1) {
            float4* bw = (float4*)(smem + ((c & 1) ^ 1) * CHUNK_BYTES);
            bw[tid]       = s0;
            bw[tid + 256] = s1;
            bw[tid + 512] = s2;
            if (w0) bw[tid + 768] = s3;
        }
        __syncthreads();
    }

    // Epilogue: tuple-min across the 16 col lanes, then write
    #pragma unroll
    for (int rt = 0; rt < 4; ++rt) {
        #pragma unroll
        for (int q = 0; q < 4; ++q) {
            float bv = best[rt][q]; int bi = bidx[rt][q];
            #pragma unroll
            for (int m = 1; m < 16; m <<= 1) {   // stays within lane&15 group
                const float ov = __shfl_xor(bv, m);
                const int   oi = __shfl_xor(bi, m);
                const bool take = (ov < bv) || (ov == bv && oi < bi);
                bv = take ? ov : bv;
                bi = take ? oi : bi;
            }
            if ((lane & 15) == 0) {
                const int row = wrow0 + rt * 16 + (lane >> 4) * 4 + q;
                wsv[(size_t)quarter * ROWS + row] = bv;
                wsi[(size_t)quarter * ROWS + row] = bi;
            }
        }
    }
}

// Kernel B: combine 8 split results (tuple-min, index tie-break = first
// occurrence), gather matched anchor, fused q_sample blend.
__global__ __launch_bounds__(256) void combine_kernel(
    const float* __restrict__ x,
    const float* __restrict__ anchors,
    const float* __restrict__ sa_tab,
    const float* __restrict__ sb_tab,
    const int*   __restrict__ t,
    const float* __restrict__ wsv,
    const int*   __restrict__ wsi,
    float* __restrict__ out)
{
    const int row = blockIdx.x * 256 + threadIdx.x;

    float bv = wsv[row];
    int   bi = wsi[row];
    #pragma unroll
    for (int qq = 1; qq < QUARTERS; ++qq) {
        const float v = wsv[(size_t)qq * ROWS + row];
        const int   i = wsi[(size_t)qq * ROWS + row];
        const bool take = (v < bv) || (v == bv && i < bi);
        bv = take ? v : bv;
        bi = take ? i : bi;
    }

    const int b  = row >> 11;            // row / N_
    const int tb = t[b];
    const float sa = sa_tab[tb];
    const float sb = sb_tab[tb];

    const float4* px = (const float4*)(x + (size_t)row * D_);
    const float4 xlo = px[0], xhi = px[1];
    const float4* pa = (const float4*)(anchors + (size_t)bi * D_);
    const float4 a0 = pa[0], a1 = pa[1];

    float4 o0, o1;
    o0.x = fmaf(sa, xlo.x, sb * a0.x);
    o0.y = fmaf(sa, xlo.y, sb * a0.y);
    o0.z = fmaf(sa, xlo.z, sb * a0.z);
    o0.w = fmaf(sa, xlo.w, sb * a0.w);
    o1.x = fmaf(sa, xhi.x, sb * a1.x);
    o1.y = fmaf(sa, xhi.y, sb * a1.y);
    o1.z = fmaf(sa, xhi.z, sb * a1.z);
    o1.w = fmaf(sa, xhi.w, sb * a1.w);

    float4* po = (float4*)(out + (size_t)row * D_);
    po[0] = o0;
    po[1] = o1;
}

extern "C" void kernel_launch(void* const* d_in, const int* in_sizes, int n_in,
                              void* d_out, int out_size, void* d_ws, size_t ws_size,
                              hipStream_t stream) {
    const float* x       = (const float*)d_in[0];  // x_start [16,2048,4,2]
    const float* anchors = (const float*)d_in[1];  // anchors [8192,4,2]
    const float* sa_tab  = (const float*)d_in[2];  // sqrt_alphas_cumprod [1000]
    const float* sb_tab  = (const float*)d_in[3];  // sqrt_one_minus_alphas_cumprod [1000]
    const int*   t       = (const int*)d_in[4];    // t [16]
    float* out = (float*)d_out;

    // ws layout: wsv [8][ROWS] f32 = 1MB @0, wsi 1MB @1MB, packed anchors
    // 426KB @2MB (total 2.43MB; harness ws held 4MB in r0-r4).
    float* wsv = (float*)d_ws;
    int*   wsi = (int*)((char*)d_ws + (size_t)1024 * 1024);
    char*  pk  = (char*)d_ws + (size_t)2048 * 1024;

    prep_kernel<<<M_ / 256, 256, 0, stream>>>(anchors, pk);

    dim3 gridA(GRIDX, QUARTERS);   // 128 x 8 = 1024 blocks (4/CU)
    argmin_mfma_kernel<<<gridA, 256, 0, stream>>>(x, pk, wsv, wsi);

    combine_kernel<<<ROWS / 256, 256, 0, stream>>>(
        x, anchors, sa_tab, sb_tab, t, wsv, wsi, out);
}

// Round 8
// 112.754 us; speedup vs baseline: 1.0579x; 1.0579x over previous
//
#include <hip/hip_runtime.h>
#include <stdint.h>

// Problem constants
#define B_      16
#define N_      2048
#define M_      8192
#define ROWS    (B_ * N_)        // 32768
#define D_      8

// ---- MFMA argmin tiling ----
#define QUARTERS 8               // anchor splits
#define APQ     (M_ / QUARTERS)  // 1024 anchors per split
#define CHUNK   256              // anchors per LDS chunk
#define NCHUNK  (APQ / CHUNK)    // 4
#define TPC     (CHUNK / 16)     // 16 MFMA tiles per chunk
#define WROWS   64               // rows per wave (4 subtiles of 16)
#define BROWS_A 256              // rows per block (4 waves)
#define GRIDX   (ROWS / BROWS_A) // 128 -> grid 128x8 = 1024 blocks (4/CU)

// Packed-anchor plane layout (same in ws prep region and LDS buffer)
#define OFF_NH  0                // [256][8] bf16 hi   (4 KB)
#define OFF_NM  4096             // [256][8] bf16 mid  (4 KB)
#define OFF_NL  8192             // [256][8] bf16 lo   (4 KB)
#define OFF_HN  12288            // [256]    f32 0.5*||a||^2 (1 KB)
#define CHUNK_BYTES 13312        // 13 KB = 13 segments of 1024 B
#define SMEM_BYTES 36864         // 36 KB declared (26 KB used): LDS governor
                                 // -> 4 blocks/CU, coherent with waves_per_eu(4,4)

// History (hard-won; keep):
//  r0-r4: scalar VALU path pinned 59-76us (practical v_fma ceiling ~103 TF).
//  r5: MFMA split-bf16 argmin correct but 116us (full unroll -> 14MB spills).
//  r6: prep kernel + unroll-2 killed spills -> 68us, 2 blocks/CU latency-bound.
//  r7: QUARTERS 4->8: only 61us. Diagnosis: allocator kept 68 ARCH VGPRs and
//    put ~wave-total-256 in AGPRs -> (a) accvgpr shuttle = 181 VALU/tile vs
//    ~60 needed (VALUBusy 64%), (b) unified-file allocation capped residency
//    at 2 blocks/CU (Occupancy 23%). One decision, both symptoms.
//  r8: amdgpu_waves_per_eu(4,4) pins the occupancy target at 4 waves/SIMD
//    (budget 128 >= live ~100) AND global_load_lds staging removes the 16
//    longest-lived VGPRs (prefetch regs held across all 16 tiles).
//  MFMA numerics: x,-a split hi/mid/lo bf16 (RNE); two 16x16x32 MFMAs give
//  8 of 9 cross terms (drop ll ~2^-36); C-input carries 0.5||a||^2.

typedef short bf16x8 __attribute__((ext_vector_type(8)));
typedef float f32x4  __attribute__((ext_vector_type(4)));

__device__ __forceinline__ unsigned short f2bf(float f) {   // RNE f32->bf16
    unsigned u = __float_as_uint(f);
    u += 0x7FFFu + ((u >> 16) & 1u);
    return (unsigned short)(u >> 16);
}
__device__ __forceinline__ float bf2f(unsigned short h) {
    return __uint_as_float(((unsigned)h) << 16);
}

// Prep: one thread per anchor; split negated anchor into bf16 hi/mid/lo +
// f32 half-norm. Chain BIT-IDENTICAL to r5/r6/r7 (verified passing).
__global__ __launch_bounds__(256) void prep_kernel(
    const float* __restrict__ anchors, char* __restrict__ pk)
{
    const int a = blockIdx.x * 256 + threadIdx.x;
    const float4* pa = (const float4*)(anchors + (size_t)a * D_);
    const float4 g0 = pa[0], g1 = pa[1];
    float nv[8] = {-g0.x, -g0.y, -g0.z, -g0.w, -g1.x, -g1.y, -g1.z, -g1.w};
    bf16x8 vh, vm, vl;
    #pragma unroll
    for (int k = 0; k < 8; ++k) {
        unsigned short h = f2bf(nv[k]);
        float r1 = nv[k] - bf2f(h);
        unsigned short m = f2bf(r1);
        float r2 = r1 - bf2f(m);
        unsigned short l = f2bf(r2);
        vh[k] = (short)h; vm[k] = (short)m; vl[k] = (short)l;
    }
    char* base = pk + (size_t)(a >> 8) * CHUNK_BYTES;
    const int i = a & 255;
    *(bf16x8*)(base + OFF_NH + i * 16) = vh;
    *(bf16x8*)(base + OFF_NM + i * 16) = vm;
    *(bf16x8*)(base + OFF_NL + i * 16) = vl;
    float nr = nv[0] * nv[0];
    #pragma unroll
    for (int k = 1; k < 8; ++k) nr = fmaf(nv[k], nv[k], nr);
    *(float*)(base + OFF_HN + i * 4) = 0.5f * nr;
}

// Kernel A: per-(row, split) (min score, argmin index) via split-bf16 MFMA.
// Wave owns 64 rows; sweeps its split's 1024 anchors in 4 double-buffered
// 13KB LDS chunks, staged by global_load_lds DMA (no staging VGPRs).
// C/D layout (m89/m91, r5-verified): col = lane&15, row = (lane>>4)*4 + reg.
__global__ __launch_bounds__(256)
__attribute__((amdgpu_waves_per_eu(4, 4)))
void argmin_mfma_kernel(
    const float* __restrict__ x,        // [ROWS][8]
    const char*  __restrict__ pk,       // packed anchors, 32 chunks
    float* __restrict__ wsv,            // [QUARTERS][ROWS]
    int*   __restrict__ wsi)            // [QUARTERS][ROWS]
{
    __shared__ __align__(16) char smem[SMEM_BYTES];

    const int tid  = threadIdx.x;
    const int wave = tid >> 6;
    const int lane = tid & 63;
    const int n    = lane & 15;          // B col / C col slot
    const int kb   = lane >> 4;          // k-block 0..3

    const int quarter = blockIdx.y;
    const int abase   = quarter * APQ;
    const int wrow0   = blockIdx.x * BROWS_A + wave * WROWS;

    const char* srcq = pk + (size_t)quarter * NCHUNK * CHUNK_BYTES;

    // Issue chunk-0 DMA first (latency hides under the A-fragment prologue).
    // 13 segments of 1024B (64 lanes x 16B); waves 0..3 take segs {w,w+4,w+8},
    // wave 0 also seg 12. LDS dest = wave-uniform base + lane*16 (m104).
    {
        char* bufw = smem;
        #pragma unroll
        for (int sg = 0; sg < 3; ++sg) {
            const int seg = (wave + sg * 4) * 1024;
            __builtin_amdgcn_global_load_lds(srcq + seg + lane * 16,
                                             bufw + seg, 16, 0, 0);
        }
        if (wave == 0)
            __builtin_amdgcn_global_load_lds(srcq + 12288 + lane * 16,
                                             bufw + 12288, 16, 0, 0);
    }

    // A fragments: x split hi/mid/lo, virtual K=32 packing
    // A1 = [xh, xm, xh, xm], A2 = [xh, xl, xm, xl]  (identical to r5-r7)
    bf16x8 A1[4], A2[4];
    #pragma unroll
    for (int rt = 0; rt < 4; ++rt) {
        const int row = wrow0 + rt * 16 + n;
        const float4* px = (const float4*)(x + (size_t)row * D_);
        const float4 lo = px[0], hi = px[1];
        const float v[8] = {lo.x, lo.y, lo.z, lo.w, hi.x, hi.y, hi.z, hi.w};
        const bool odd = (kb & 1);
        const bool is2 = (kb == 2);
        #pragma unroll
        for (int k = 0; k < 8; ++k) {
            unsigned short xh = f2bf(v[k]);
            float r1 = v[k] - bf2f(xh);
            unsigned short xm = f2bf(r1);
            float r2 = r1 - bf2f(xm);
            unsigned short xl = f2bf(r2);
            A1[rt][k] = (short)(odd ? xm : xh);
            A2[rt][k] = (short)(odd ? xl : (is2 ? xm : xh));
        }
    }

    // Per-lane LDS read offsets. B1 = [nh,nh,nm,nm]; B2 = [nl,nh,nl,nm].
    const int o1 = ((kb < 2) ? OFF_NH : OFF_NM) + n * 16;
    const int o2 = ((kb == 1) ? OFF_NH : (kb == 3) ? OFF_NM : OFF_NL) + n * 16;
    const int oh = OFF_HN + n * 4;

    float best[4][4];
    int   bidx[4][4];
    #pragma unroll
    for (int rt = 0; rt < 4; ++rt)
        #pragma unroll
        for (int q = 0; q < 4; ++q) { best[rt][q] = 3.4e38f; bidx[rt][q] = 0; }

    int idxv = abase + n;

    __syncthreads();                     // drains chunk-0 DMA (vmcnt in barrier)

    #pragma unroll 1
    for (int c = 0; c < NCHUNK; ++c) {
        const char* bufr = smem + (c & 1) * CHUNK_BYTES;

        // Prefetch next chunk via DMA into the other buffer (in flight
        // across this chunk's 16 tiles; drained by the end barrier).
        if (c < NCHUNK - 1) {
            char* bufw = smem + ((c & 1) ^ 1) * CHUNK_BYTES;
            const char* g = srcq + (size_t)(c + 1) * CHUNK_BYTES;
            #pragma unroll
            for (int sg = 0; sg < 3; ++sg) {
                const int seg = (wave + sg * 4) * 1024;
                __builtin_amdgcn_global_load_lds(g + seg + lane * 16,
                                                 bufw + seg, 16, 0, 0);
            }
            if (wave == 0)
                __builtin_amdgcn_global_load_lds(g + 12288 + lane * 16,
                                                 bufw + 12288, 16, 0, 0);
        }

        #pragma unroll 2
        for (int tt = 0; tt < TPC; ++tt) {
            const bf16x8 b1 = *(const bf16x8*)(bufr + o1 + tt * 256);
            const bf16x8 b2 = *(const bf16x8*)(bufr + o2 + tt * 256);
            const float  hn = *(const float*)(bufr + oh + tt * 64);
            const f32x4 cvec = {hn, hn, hn, hn};
            #pragma unroll
            for (int rt = 0; rt < 4; ++rt) {
                f32x4 acc = __builtin_amdgcn_mfma_f32_16x16x32_bf16(A1[rt], b1, cvec, 0, 0, 0);
                acc = __builtin_amdgcn_mfma_f32_16x16x32_bf16(A2[rt], b2, acc, 0, 0, 0);
                #pragma unroll
                for (int q = 0; q < 4; ++q) {
                    const bool lt = acc[q] < best[rt][q];   // strict '<': keeps
                    best[rt][q] = lt ? acc[q] : best[rt][q];// earliest index
                    bidx[rt][q] = lt ? idxv   : bidx[rt][q];
                }
            }
            idxv += 16;
        }

        __syncthreads();
    }

    // Epilogue: tuple-min across the 16 col lanes, then write
    #pragma unroll
    for (int rt = 0; rt < 4; ++rt) {
        #pragma unroll
        for (int q = 0; q < 4; ++q) {
            float bv = best[rt][q]; int bi = bidx[rt][q];
            #pragma unroll
            for (int m = 1; m < 16; m <<= 1) {   // stays within lane&15 group
                const float ov = __shfl_xor(bv, m);
                const int   oi = __shfl_xor(bi, m);
                const bool take = (ov < bv) || (ov == bv && oi < bi);
                bv = take ? ov : bv;
                bi = take ? oi : bi;
            }
            if ((lane & 15) == 0) {
                const int row = wrow0 + rt * 16 + (lane >> 4) * 4 + q;
                wsv[(size_t)quarter * ROWS + row] = bv;
                wsi[(size_t)quarter * ROWS + row] = bi;
            }
        }
    }
}

// Kernel B: combine 8 split results (tuple-min, index tie-break = first
// occurrence), gather matched anchor, fused q_sample blend.
__global__ __launch_bounds__(256) void combine_kernel(
    const float* __restrict__ x,
    const float* __restrict__ anchors,
    const float* __restrict__ sa_tab,
    const float* __restrict__ sb_tab,
    const int*   __restrict__ t,
    const float* __restrict__ wsv,
    const int*   __restrict__ wsi,
    float* __restrict__ out)
{
    const int row = blockIdx.x * 256 + threadIdx.x;

    float bv = wsv[row];
    int   bi = wsi[row];
    #pragma unroll
    for (int qq = 1; qq < QUARTERS; ++qq) {
        const float v = wsv[(size_t)qq * ROWS + row];
        const int   i = wsi[(size_t)qq * ROWS + row];
        const bool take = (v < bv) || (v == bv && i < bi);
        bv = take ? v : bv;
        bi = take ? i : bi;
    }

    const int b  = row >> 11;            // row / N_
    const int tb = t[b];
    const float sa = sa_tab[tb];
    const float sb = sb_tab[tb];

    const float4* px = (const float4*)(x + (size_t)row * D_);
    const float4 xlo = px[0], xhi = px[1];
    const float4* pa = (const float4*)(anchors + (size_t)bi * D_);
    const float4 a0 = pa[0], a1 = pa[1];

    float4 o0, o1;
    o0.x = fmaf(sa, xlo.x, sb * a0.x);
    o0.y = fmaf(sa, xlo.y, sb * a0.y);
    o0.z = fmaf(sa, xlo.z, sb * a0.z);
    o0.w = fmaf(sa, xlo.w, sb * a0.w);
    o1.x = fmaf(sa, xhi.x, sb * a1.x);
    o1.y = fmaf(sa, xhi.y, sb * a1.y);
    o1.z = fmaf(sa, xhi.z, sb * a1.z);
    o1.w = fmaf(sa, xhi.w, sb * a1.w);

    float4* po = (float4*)(out + (size_t)row * D_);
    po[0] = o0;
    po[1] = o1;
}

extern "C" void kernel_launch(void* const* d_in, const int* in_sizes, int n_in,
                              void* d_out, int out_size, void* d_ws, size_t ws_size,
                              hipStream_t stream) {
    const float* x       = (const float*)d_in[0];  // x_start [16,2048,4,2]
    const float* anchors = (const float*)d_in[1];  // anchors [8192,4,2]
    const float* sa_tab  = (const float*)d_in[2];  // sqrt_alphas_cumprod [1000]
    const float* sb_tab  = (const float*)d_in[3];  // sqrt_one_minus_alphas_cumprod [1000]
    const int*   t       = (const int*)d_in[4];    // t [16]
    float* out = (float*)d_out;

    // ws layout: wsv [8][ROWS] f32 = 1MB @0, wsi 1MB @1MB, packed anchors
    // 426KB @2MB (total 2.43MB; harness ws held 4MB in r0-r4).
    float* wsv = (float*)d_ws;
    int*   wsi = (int*)((char*)d_ws + (size_t)1024 * 1024);
    char*  pk  = (char*)d_ws + (size_t)2048 * 1024;

    prep_kernel<<<M_ / 256, 256, 0, stream>>>(anchors, pk);

    dim3 gridA(GRIDX, QUARTERS);   // 128 x 8 = 1024 blocks (4/CU)
    argmin_mfma_kernel<<<gridA, 256, 0, stream>>>(x, pk, wsv, wsi);

    combine_kernel<<<ROWS / 256, 256, 0, stream>>>(
        x, anchors, sa_tab, sb_tab, t, wsv, wsi, out);
}